// Round 4
// baseline (350.532 us; speedup 1.0000x reference)
//
#include <hip/hip_runtime.h>

typedef short v8s __attribute__((ext_vector_type(8)));
typedef float v4f __attribute__((ext_vector_type(4)));
using u16 = unsigned short;

__device__ __forceinline__ u16 f2b(float f) {
  union { float f; unsigned u; } v; v.f = f;
  unsigned r = v.u + 0x7FFFu + ((v.u >> 16) & 1u);
  return (u16)(r >> 16);
}

// ---------------- LayerNorm + bf16 casts ----------------
__global__ void ln_prep(const float* __restrict__ x, const float* __restrict__ ctx,
                        const float* __restrict__ gamma, const float* __restrict__ beta,
                        float* __restrict__ xn_f, u16* __restrict__ xn_b,
                        u16* __restrict__ ctx_b)
{
  const int tid = threadIdx.x;
  if (blockIdx.y == 0) {
    const int wid = tid >> 6, lane = tid & 63;
    const int row = blockIdx.x * 4 + wid;
    const float4 xv = *(const float4*)(x + (size_t)row * 256 + lane * 4);
    float s1 = xv.x + xv.y + xv.z + xv.w;
    float s2 = xv.x*xv.x + xv.y*xv.y + xv.z*xv.z + xv.w*xv.w;
#pragma unroll
    for (int m = 32; m >= 1; m >>= 1) {
      s1 += __shfl_xor(s1, m);
      s2 += __shfl_xor(s2, m);
    }
    const float mu  = s1 * (1.0f/256.0f);
    const float var = s2 * (1.0f/256.0f) - mu*mu;
    const float rs  = rsqrtf(var + 1e-3f);
    const float4 g = *(const float4*)(gamma + lane*4);
    const float4 b = *(const float4*)(beta  + lane*4);
    float4 y;
    y.x = (xv.x-mu)*rs*g.x + b.x;
    y.y = (xv.y-mu)*rs*g.y + b.y;
    y.z = (xv.z-mu)*rs*g.z + b.z;
    y.w = (xv.w-mu)*rs*g.w + b.w;
    *(float4*)(xn_f + (size_t)row*256 + lane*4) = y;
    ushort4 yb; yb.x=f2b(y.x); yb.y=f2b(y.y); yb.z=f2b(y.z); yb.w=f2b(y.w);
    *(ushort4*)(xn_b + (size_t)row*256 + lane*4) = yb;
  } else {
    const size_t idx = (size_t)blockIdx.x * 1024 + (size_t)tid * 4;
    const float4 cv = *(const float4*)(ctx + idx);
    ushort4 cb; cb.x=f2b(cv.x); cb.y=f2b(cv.y); cb.z=f2b(cv.z); cb.w=f2b(cv.w);
    *(ushort4*)(ctx_b + idx) = cb;
  }
}

// ---------------- weight transpose + bf16 cast (LDS-tiled) ----------------
// grid (16, 4), block 256. Both global sides coalesced; LDS pad +1 kills conflicts.
__global__ void wtrans(const float* __restrict__ wq, const float* __restrict__ wk,
                       const float* __restrict__ wv, const float* __restrict__ wp,
                       u16* __restrict__ tq, u16* __restrict__ tk,
                       u16* __restrict__ tv, u16* __restrict__ tp)
{
  const float* src; u16* dst;
  switch (blockIdx.y) {
    case 0:  src = wq; dst = tq; break;
    case 1:  src = wk; dst = tk; break;
    case 2:  src = wv; dst = tv; break;
    default: src = wp; dst = tp; break;
  }
  __shared__ float tile[64][65];
  const int t = threadIdx.x;
  const int r0 = (blockIdx.x & 3) * 64, c0 = (blockIdx.x >> 2) * 64;
  const int c = t & 63, r = t >> 6;
#pragma unroll
  for (int j = 0; j < 16; j++)
    tile[r + j*4][c] = src[(size_t)(r0 + r + j*4) * 256 + c0 + c];
  __syncthreads();
#pragma unroll
  for (int j = 0; j < 16; j++)
    dst[(size_t)(c0 + r + j*4) * 256 + r0 + c] = f2b(tile[c][r + j*4]);
}

// ---------------- q/k/v GEMM ----------------
__global__ __launch_bounds__(256) void gemm_qkv(
    const u16* __restrict__ xn_b, const u16* __restrict__ ctx_b,
    const u16* __restrict__ wqt, const u16* __restrict__ wkt, const u16* __restrict__ wvt,
    const float* __restrict__ bq, const float* __restrict__ bk, const float* __restrict__ bv,
    u16* __restrict__ qo, u16* __restrict__ ko, u16* __restrict__ vto)
{
  const int mode = blockIdx.y;
  const u16* A; const u16* Wt; const float* bias;
  if (mode == 0)      { A = xn_b;  Wt = wqt; bias = bq; }
  else if (mode == 1) { A = ctx_b; Wt = wkt; bias = bk; }
  else                { A = ctx_b; Wt = wvt; bias = bv; }
  const int wid = threadIdx.x >> 6, lane = threadIdx.x & 63;
  const int lm = lane & 15, q4 = lane >> 4;
  const int m0 = blockIdx.x * 64 + wid * 16;
  const u16* arow = A + (size_t)(m0 + lm) * 256 + q4 * 8;
  v8s af[8];
#pragma unroll
  for (int kf = 0; kf < 8; kf++) af[kf] = *(const v8s*)(arow + kf * 32);
#pragma unroll
  for (int ct = 0; ct < 16; ct++) {
    const int c = ct * 16 + lm;
    const u16* wrow = Wt + (size_t)c * 256 + q4 * 8;
    v4f acc = {0.f, 0.f, 0.f, 0.f};
#pragma unroll
    for (int kf = 0; kf < 8; kf++)
      acc = __builtin_amdgcn_mfma_f32_16x16x32_bf16(af[kf], *(const v8s*)(wrow + kf * 32), acc, 0, 0, 0);
    const float bb = bias[c];
    if (mode == 2) {
      const int b = m0 >> 12;
      const int s = (m0 & 4095) + q4 * 4;
      ushort4 pk;
      pk.x = f2b(acc[0] + bb); pk.y = f2b(acc[1] + bb);
      pk.z = f2b(acc[2] + bb); pk.w = f2b(acc[3] + bb);
      *(ushort4*)(vto + (size_t)b * 1048576 + (size_t)c * 4096 + s) = pk;
    } else {
      u16* out = (mode == 0) ? qo : ko;
#pragma unroll
      for (int r = 0; r < 4; r++)
        out[(size_t)(m0 + q4 * 4 + r) * 256 + c] = f2b(acc[r] + bb);
    }
  }
}

// ---------------- flash-style attention, v4 ----------------
// Block = 512 threads (8 waves) on 64 Q rows; 128-key chunks.
//   phase A: wave w -> score strip S[64q x 16 keys (w*16..)], exp -> P (LDS dbuf)
//   phase B: wave w -> O[64q x 32 ch (w*32..)] += P * V   (channel split => no
//            O duplication across waves, no combine pass)
// K/V straight from global (L2-hot, no intra-block duplication). One barrier
// per chunk. 8 waves = 2 waves/SIMD so MFMA of one wave hides the other's
// vmcnt/barrier waits. ~37 KB LDS.
__global__ __launch_bounds__(512, 2) void attn_kernel(
    const u16* __restrict__ q, const u16* __restrict__ k,
    const u16* __restrict__ vt, u16* __restrict__ ao)
{
  __shared__ u16 P[2][64][136];   // [buf][q][key] bf16, 34.8 KB
  __shared__ float Lp[8][64];
  __shared__ float Lt[64];
  const int b   = blockIdx.y;
  const int tid = threadIdx.x;
  const int w   = tid >> 6, lane = tid & 63;
  const int lm  = lane & 15, q4 = lane >> 4;
  const int m0  = blockIdx.x * 64;
  const u16* qb = q  + (size_t)b * 4096 * 256;
  const u16* kb = k  + (size_t)b * 4096 * 256;
  const u16* vb = vt + (size_t)b * 256 * 4096;

  // Q fragments for 4 q-tiles, held all kernel (128 VGPR)
  v8s qf[4][8];
#pragma unroll
  for (int qt = 0; qt < 4; qt++) {
    const u16* qrow = qb + (size_t)(m0 + qt * 16 + lm) * 256 + q4 * 8;
#pragma unroll
    for (int kf = 0; kf < 8; kf++) qf[qt][kf] = *(const v8s*)(qrow + kf * 32);
  }

  v4f o[4][2];
#pragma unroll
  for (int qt = 0; qt < 4; qt++) { o[qt][0] = (v4f){0,0,0,0}; o[qt][1] = (v4f){0,0,0,0}; }
  float lsum[4][4];
#pragma unroll
  for (int qt = 0; qt < 4; qt++)
#pragma unroll
    for (int r = 0; r < 4; r++) lsum[qt][r] = 0.f;

  // K fragments for chunk 0: this wave's 16-key strip
  v8s ka[8], kn[8];
  {
    const u16* krow = kb + (size_t)(w * 16 + lm) * 256 + q4 * 8;
#pragma unroll
    for (int kf = 0; kf < 8; kf++) ka[kf] = *(const v8s*)(krow + kf * 32);
  }

  for (int s0 = 0; s0 < 4096; s0 += 128) {
    const int pb = (s0 >> 7) & 1;
    // V loads for this chunk: wave's 32-ch strip x 128 keys (issued early,
    // consumed after phase A -> latency covered by 32 MFMA + other wave)
    v8s vf[2][4];
#pragma unroll
    for (int ct = 0; ct < 2; ct++) {
      const u16* vrow = vb + (size_t)(w * 32 + ct * 16 + lm) * 4096 + s0 + q4 * 8;
#pragma unroll
      for (int kf = 0; kf < 4; kf++) vf[ct][kf] = *(const v8s*)(vrow + kf * 32);
    }
    // phase A: S[64q x 16k]
    v4f sc[4];
#pragma unroll
    for (int qt = 0; qt < 4; qt++) sc[qt] = (v4f){0,0,0,0};
#pragma unroll
    for (int kf = 0; kf < 8; kf++)
#pragma unroll
      for (int qt = 0; qt < 4; qt++)
        sc[qt] = __builtin_amdgcn_mfma_f32_16x16x32_bf16(qf[qt][kf], ka[kf], sc[qt], 0, 0, 0);
    // K prefetch for next chunk
    {
      const int sn = (s0 + 128) & 4095;
      const u16* krn = kb + (size_t)(sn + w * 16 + lm) * 256 + q4 * 8;
#pragma unroll
      for (int kf = 0; kf < 8; kf++) kn[kf] = *(const v8s*)(krn + kf * 32);
    }
    // exp -> P  (C layout: row = qt*16 + q4*4 + r, col = w*16 + lm)
#pragma unroll
    for (int qt = 0; qt < 4; qt++)
#pragma unroll
      for (int r = 0; r < 4; r++) {
        const float e = __expf(sc[qt][r] * 0.0625f);
        lsum[qt][r] += e;
        P[pb][qt * 16 + q4 * 4 + r][w * 16 + lm] = f2b(e);
      }
    __syncthreads();
    // phase B: O[64q x 32ch(w)] += P * V over 128 keys
#pragma unroll
    for (int qt = 0; qt < 4; qt++) {
#pragma unroll
      for (int kf = 0; kf < 4; kf++) {
        const v8s pf = *(const v8s*)(&P[pb][qt * 16 + lm][kf * 32 + q4 * 8]);
        o[qt][0] = __builtin_amdgcn_mfma_f32_16x16x32_bf16(pf, vf[0][kf], o[qt][0], 0, 0, 0);
        o[qt][1] = __builtin_amdgcn_mfma_f32_16x16x32_bf16(pf, vf[1][kf], o[qt][1], 0, 0, 0);
      }
    }
#pragma unroll
    for (int kf = 0; kf < 8; kf++) ka[kf] = kn[kf];
  }

  // l: butterfly over the 16 key-lanes, publish per-wave partials, sum 8 waves
#pragma unroll
  for (int qt = 0; qt < 4; qt++)
#pragma unroll
    for (int r = 0; r < 4; r++) {
      float t = lsum[qt][r];
      t += __shfl_xor(t, 1); t += __shfl_xor(t, 2);
      t += __shfl_xor(t, 4); t += __shfl_xor(t, 8);
      lsum[qt][r] = t;
    }
  if (lm == 0) {
#pragma unroll
    for (int qt = 0; qt < 4; qt++)
#pragma unroll
      for (int r = 0; r < 4; r++) Lp[w][qt * 16 + q4 * 4 + r] = lsum[qt][r];
  }
  __syncthreads();
  if (tid < 64) {
    float s = 0.f;
#pragma unroll
    for (int ww = 0; ww < 8; ww++) s += Lp[ww][tid];
    Lt[tid] = 1.0f / s;
  }
  __syncthreads();

  u16* aob = ao + ((size_t)b * 4096 + m0) * 256;
#pragma unroll
  for (int qt = 0; qt < 4; qt++)
#pragma unroll
    for (int r = 0; r < 4; r++) {
      const float linv = Lt[qt * 16 + q4 * 4 + r];
      const size_t base = (size_t)(qt * 16 + q4 * 4 + r) * 256 + w * 32;
      aob[base + lm]      = f2b(o[qt][0][r] * linv);
      aob[base + 16 + lm] = f2b(o[qt][1][r] * linv);
    }
}

// ---------------- proj GEMM + bias + residual ----------------
__global__ __launch_bounds__(256) void gemm_proj(
    const u16* __restrict__ A, const u16* __restrict__ Wt, const float* __restrict__ bias,
    const float* __restrict__ xn_f, float* __restrict__ out)
{
  const int wid = threadIdx.x >> 6, lane = threadIdx.x & 63;
  const int lm = lane & 15, q4 = lane >> 4;
  const int m0 = blockIdx.x * 64 + wid * 16;
  const u16* arow = A + (size_t)(m0 + lm) * 256 + q4 * 8;
  v8s af[8];
#pragma unroll
  for (int kf = 0; kf < 8; kf++) af[kf] = *(const v8s*)(arow + kf * 32);
#pragma unroll
  for (int ct = 0; ct < 16; ct++) {
    const int c = ct * 16 + lm;
    const u16* wrow = Wt + (size_t)c * 256 + q4 * 8;
    v4f acc = {0.f, 0.f, 0.f, 0.f};
#pragma unroll
    for (int kf = 0; kf < 8; kf++)
      acc = __builtin_amdgcn_mfma_f32_16x16x32_bf16(af[kf], *(const v8s*)(wrow + kf * 32), acc, 0, 0, 0);
    const float bb = bias[c];
#pragma unroll
    for (int r = 0; r < 4; r++) {
      const size_t idx = (size_t)(m0 + q4 * 4 + r) * 256 + c;
      out[idx] = xn_f[idx] + acc[r] + bb;
    }
  }
}

extern "C" void kernel_launch(void* const* d_in, const int* in_sizes, int n_in,
                              void* d_out, int out_size, void* d_ws, size_t ws_size,
                              hipStream_t stream)
{
  (void)in_sizes; (void)n_in; (void)out_size; (void)ws_size;
  const float* inputs  = (const float*)d_in[0];
  const float* context = (const float*)d_in[1];
  const float* Wq = (const float*)d_in[2];
  const float* bq = (const float*)d_in[3];
  const float* Wk = (const float*)d_in[4];
  const float* bk = (const float*)d_in[5];
  const float* Wv = (const float*)d_in[6];
  const float* bv = (const float*)d_in[7];
  const float* Wp = (const float*)d_in[8];
  const float* bp = (const float*)d_in[9];
  const float* gamma = (const float*)d_in[10];
  const float* beta  = (const float*)d_in[11];
  float* out = (float*)d_out;

  char* p = (char*)d_ws;
  float* xn_f = (float*)p; p += (size_t)16384 * 256 * 4;
  u16* xn_b   = (u16*)p;   p += (size_t)16384 * 256 * 2;
  u16* ctx_b  = (u16*)p;   p += (size_t)16384 * 256 * 2;
  u16* qbuf   = (u16*)p;   p += (size_t)16384 * 256 * 2;
  u16* kbuf   = (u16*)p;   p += (size_t)16384 * 256 * 2;
  u16* vtbuf  = (u16*)p;   p += (size_t)16384 * 256 * 2;
  u16* wqt = (u16*)p; p += (size_t)256 * 256 * 2;
  u16* wkt = (u16*)p; p += (size_t)256 * 256 * 2;
  u16* wvt = (u16*)p; p += (size_t)256 * 256 * 2;
  u16* wpt = (u16*)p; p += (size_t)256 * 256 * 2;
  u16* aobuf = xn_b;  // xn_b dead after gemm_qkv

  ln_prep<<<dim3(4096, 2), 256, 0, stream>>>(inputs, context, gamma, beta, xn_f, xn_b, ctx_b);
  wtrans<<<dim3(16, 4), 256, 0, stream>>>(Wq, Wk, Wv, Wp, wqt, wkt, wvt, wpt);
  gemm_qkv<<<dim3(256, 3), 256, 0, stream>>>(xn_b, ctx_b, wqt, wkt, wvt, bq, bk, bv, qbuf, kbuf, vtbuf);
  attn_kernel<<<dim3(64, 4), 512, 0, stream>>>(qbuf, kbuf, vtbuf, aobuf);
  gemm_proj<<<dim3(256), 256, 0, stream>>>(aobuf, wpt, bp, xn_f, out);
}